// Round 10
// baseline (273.087 us; speedup 1.0000x reference)
//
#include <hip/hip_runtime.h>
#include <cstdint>
#include <cstddef>

#define B_ 16
#define S_ 2048
#define D_ 128

typedef float  f32x4 __attribute__((ext_vector_type(4)));
typedef _Float16 f16x8 __attribute__((ext_vector_type(8)));
typedef _Float16 f16x4 __attribute__((ext_vector_type(4)));

// log2(e) / sqrt(128)
#define SCALE_ 0.12751743f

#define NE_ ((size_t)B_ * S_ * D_)   // 4,194,304 per tensor
#define VT2_BATCH 262144             // halves per batch in Vt2 (=512KB f16)

// ---------------- pre-pass (verified R5-R9) ----------------
// blocks [0,2048): V -> Vt2, PV-fragment-native tiled layout:
//   Vt2[((b*128 + kt)*8 + dt)*64 + lane][i]  (f16, i=0..3)
//   holds V[b][key = kt*16 + 4*(lane>>4) + i][d = dt*16 + (lane&15)]
// blocks [2048,3072): K f32 -> f16 row-major
__global__ void prepass_kernel(const float* __restrict__ K,
                               const float* __restrict__ V,
                               _Float16* __restrict__ Kh,
                               _Float16* __restrict__ Vt2) {
  const int blk = blockIdx.x;
  if (blk < 2048) {
    const int b  = blk >> 7;
    const int kt = blk & 127;
    const int tid = threadIdx.x;
    const int lg = tid >> 6;
    const int i  = (tid >> 4) & 3;
    const int lr = tid & 15;
    const size_t vrow = ((size_t)b * S_ + kt * 16 + 4 * lg + i) * D_;
    const size_t obase = (((size_t)(b * 128 + kt) * 8) * 64 + lg * 16 + lr) * 4 + i;
#pragma unroll
    for (int dt = 0; dt < 8; ++dt) {
      float val = V[vrow + dt * 16 + lr];
      Vt2[obase + (size_t)dt * 256] = (_Float16)val;
    }
  } else {
    int rel = blk - 2048;
    const int n4 = (int)(NE_ / 4);
    for (int i = rel * 256 + (int)threadIdx.x; i < n4; i += 1024 * 256) {
      f32x4 v = ((const f32x4*)K)[i];
      f16x4 h;
      for (int j = 0; j < 4; ++j) h[j] = (_Float16)v[j];
      ((f16x4*)Kh)[i] = h;
    }
  }
}

// ---------------- kernel 2: row-sum denominators ----------------
// 256 blocks x 256 thr; wave = 32 q-rows x all 2048 keys. Swapped QK^T
// (A=K rows, B=Q rows); psum per lane covers keys {16kt+4lg+r}; reduce
// over lg via shfl_xor(16),(32). Writes inv = 1/sum (fixed order, det).
template <bool WS>
__global__ __launch_bounds__(256, 4)
void sums_kernel(const float* __restrict__ Qf, const float* __restrict__ Kf,
                 const _Float16* __restrict__ Kh, float* __restrict__ invbuf) {
  const int tid = threadIdx.x;
  const int w = tid >> 6, lane = tid & 63, lg = lane >> 4, lr = lane & 15;
  const int blk = blockIdx.x;
  // XCD-local: xcd = blk&7 handles batches {2*xcd, 2*xcd+1}
  const int gwid = ((blk & 7) * 32 + (blk >> 3)) * 4 + w;   // 0..1023
  const int b  = gwid >> 6;
  const int q0 = (gwid & 63) * 32;

  f16x8 bq[2][4];
#pragma unroll
  for (int h = 0; h < 2; ++h) {
    const float* qp = Qf + ((size_t)b * S_ + q0 + 16 * h + lr) * D_;
#pragma unroll
    for (int kk = 0; kk < 4; ++kk) {
      const float* p = qp + kk * 32 + lg * 8;
      f32x4 v0 = *(const f32x4*)p, v1 = *(const f32x4*)(p + 4);
      f16x8 a;
#pragma unroll
      for (int j = 0; j < 4; ++j) { a[j] = (_Float16)v0[j]; a[4 + j] = (_Float16)v1[j]; }
      bq[h][kk] = a;
    }
  }

  float psum0 = 0.f, psum1 = 0.f;
#pragma unroll 2
  for (int kt = 0; kt < 128; ++kt) {
    f32x4 acc0 = {0.f, 0.f, 0.f, 0.f}, acc1 = {0.f, 0.f, 0.f, 0.f};
    const size_t krow = (size_t)b * S_ + kt * 16 + lr;
#pragma unroll
    for (int kk = 0; kk < 4; ++kk) {
      f16x8 ka;
      if constexpr (WS) {
        ka = *(const f16x8*)(Kh + krow * D_ + kk * 32 + lg * 8);
      } else {
        const float* p = Kf + krow * D_ + kk * 32 + lg * 8;
        f32x4 v0 = *(const f32x4*)p, v1 = *(const f32x4*)(p + 4);
#pragma unroll
        for (int j = 0; j < 4; ++j) { ka[j] = (_Float16)v0[j]; ka[4 + j] = (_Float16)v1[j]; }
      }
      acc0 = __builtin_amdgcn_mfma_f32_16x16x32_f16(ka, bq[0][kk], acc0, 0, 0, 0);
      acc1 = __builtin_amdgcn_mfma_f32_16x16x32_f16(ka, bq[1][kk], acc1, 0, 0, 0);
    }
#pragma unroll
    for (int r = 0; r < 4; ++r) {
      psum0 += __builtin_amdgcn_exp2f(acc0[r] * SCALE_);
      psum1 += __builtin_amdgcn_exp2f(acc1[r] * SCALE_);
    }
  }
  psum0 += __shfl_xor(psum0, 16); psum0 += __shfl_xor(psum0, 32);
  psum1 += __shfl_xor(psum1, 16); psum1 += __shfl_xor(psum1, 32);
  if (lg == 0) {
    invbuf[(size_t)b * S_ + q0 + lr]      = 1.0f / psum0;
    invbuf[(size_t)b * S_ + q0 + 16 + lr] = 1.0f / psum1;
  }
}

// ---------------- kernel 3: barrier-free streaming attention ----------------
// 512 blocks x 256 thr; wave = 16 q-rows x all 2048 keys, fully independent:
// zero LDS, zero barriers. inv is precomputed -> normalized attn rows are
// stored INSIDE the k-loop from iteration 0 (continuous write stream, no
// convoy). PV accumulates o[8] across the same loop (compile-time indices
// only -- runtime-indexed reg arrays spill to scratch, R5/R6 lesson).
// Fragment math verbatim from verified R5-R9: S^T = mfma16x16x32(A=K,B=Q),
// lane(lr,lg) reg r holds S^T[key=16kt+4lg+r][qrow=lr]; packed f16x4 is the
// A-frag of mfma_f32_16x16x16_f16; PV D gives O[qrow=4lg+r][d=16dt+lr].
template <bool WS>
__global__ __launch_bounds__(256, 2)
void attn_main(const float* __restrict__ Qf, const float* __restrict__ Kf,
               const float* __restrict__ Vf,
               const _Float16* __restrict__ Kh, const _Float16* __restrict__ Vt2,
               const float* __restrict__ invbuf,
               float* __restrict__ outO, float* __restrict__ outA) {
  const int tid = threadIdx.x;
  const int w = tid >> 6, lane = tid & 63, lg = lane >> 4, lr = lane & 15;
  const int blk = blockIdx.x;
  // XCD-local: xcd = blk&7 handles batches {2*xcd, 2*xcd+1}
  const int gwid = ((blk & 7) * 64 + (blk >> 3)) * 4 + w;   // 0..2047
  const int b  = gwid >> 7;
  const int q0 = (gwid & 127) * 16;

  // inverse denominators: inv for attn rows (row=lr), inv4 for O rows (4lg+r)
  const float inv = invbuf[(size_t)b * S_ + q0 + lr];
  f32x4 inv4;
#pragma unroll
  for (int r = 0; r < 4; ++r) inv4[r] = __shfl(inv, 4 * lg + r);

  // Q B-frags: B[k=32kk+8lg+j][n=qrow=lr]
  f16x8 bq[4];
  {
    const float* qp = Qf + ((size_t)b * S_ + q0 + lr) * D_;
#pragma unroll
    for (int kk = 0; kk < 4; ++kk) {
      const float* p = qp + kk * 32 + lg * 8;
      f32x4 v0 = *(const f32x4*)p, v1 = *(const f32x4*)(p + 4);
      f16x8 a;
#pragma unroll
      for (int j = 0; j < 4; ++j) { a[j] = (_Float16)v0[j]; a[4 + j] = (_Float16)v1[j]; }
      bq[kk] = a;
    }
  }

  f32x4 o0 = {0.f,0.f,0.f,0.f}, o1 = {0.f,0.f,0.f,0.f}, o2 = {0.f,0.f,0.f,0.f},
        o3 = {0.f,0.f,0.f,0.f}, o4 = {0.f,0.f,0.f,0.f}, o5 = {0.f,0.f,0.f,0.f},
        o6 = {0.f,0.f,0.f,0.f}, o7 = {0.f,0.f,0.f,0.f};

  const _Float16* vbase = Vt2 + (size_t)b * VT2_BATCH + lane * 4;
  float* arow = outA + ((size_t)b * S_ + q0 + lr) * S_ + lg * 4;

#pragma unroll 2
  for (int kt = 0; kt < 128; ++kt) {
    // ---- QK^T tile ----
    f32x4 acc = {0.f, 0.f, 0.f, 0.f};
    const size_t krow = (size_t)b * S_ + kt * 16 + lr;
#pragma unroll
    for (int kk = 0; kk < 4; ++kk) {
      f16x8 ka;
      if constexpr (WS) {
        ka = *(const f16x8*)(Kh + krow * D_ + kk * 32 + lg * 8);
      } else {
        const float* p = Kf + krow * D_ + kk * 32 + lg * 8;
        f32x4 v0 = *(const f32x4*)p, v1 = *(const f32x4*)(p + 4);
#pragma unroll
        for (int j = 0; j < 4; ++j) { ka[j] = (_Float16)v0[j]; ka[4 + j] = (_Float16)v1[j]; }
      }
      acc = __builtin_amdgcn_mfma_f32_16x16x32_f16(ka, bq[kk], acc, 0, 0, 0);
    }
    // ---- exp, normalized attn store (immediately), f16 pack ----
    f32x4 av; f16x4 p;
#pragma unroll
    for (int r = 0; r < 4; ++r) {
      float e = __builtin_amdgcn_exp2f(acc[r] * SCALE_);
      av[r] = e * inv;
      p[r]  = (_Float16)e;          // unnormalized for PV; O scaled at end
    }
    __builtin_nontemporal_store(av, (f32x4*)(arow + kt * 16));
    // ---- PV accumulate: p IS the 16x16x16 A-frag ----
    const _Float16* vk = vbase + (size_t)kt * 2048;
    f16x4 bv0, bv1, bv2, bv3, bv4, bv5, bv6, bv7;
    if constexpr (WS) {
      bv0 = *(const f16x4*)(vk);        bv1 = *(const f16x4*)(vk + 256);
      bv2 = *(const f16x4*)(vk + 512);  bv3 = *(const f16x4*)(vk + 768);
      bv4 = *(const f16x4*)(vk + 1024); bv5 = *(const f16x4*)(vk + 1280);
      bv6 = *(const f16x4*)(vk + 1536); bv7 = *(const f16x4*)(vk + 1792);
    } else {
      const float* vrow = Vf + ((size_t)b * S_ + kt * 16 + 4 * lg) * D_ + lr;
#pragma unroll
      for (int i = 0; i < 4; ++i) {
        bv0[i] = (_Float16)vrow[(size_t)i * D_];
        bv1[i] = (_Float16)vrow[(size_t)i * D_ + 16];
        bv2[i] = (_Float16)vrow[(size_t)i * D_ + 32];
        bv3[i] = (_Float16)vrow[(size_t)i * D_ + 48];
        bv4[i] = (_Float16)vrow[(size_t)i * D_ + 64];
        bv5[i] = (_Float16)vrow[(size_t)i * D_ + 80];
        bv6[i] = (_Float16)vrow[(size_t)i * D_ + 96];
        bv7[i] = (_Float16)vrow[(size_t)i * D_ + 112];
      }
    }
    o0 = __builtin_amdgcn_mfma_f32_16x16x16f16(p, bv0, o0, 0, 0, 0);
    o1 = __builtin_amdgcn_mfma_f32_16x16x16f16(p, bv1, o1, 0, 0, 0);
    o2 = __builtin_amdgcn_mfma_f32_16x16x16f16(p, bv2, o2, 0, 0, 0);
    o3 = __builtin_amdgcn_mfma_f32_16x16x16f16(p, bv3, o3, 0, 0, 0);
    o4 = __builtin_amdgcn_mfma_f32_16x16x16f16(p, bv4, o4, 0, 0, 0);
    o5 = __builtin_amdgcn_mfma_f32_16x16x16f16(p, bv5, o5, 0, 0, 0);
    o6 = __builtin_amdgcn_mfma_f32_16x16x16f16(p, bv6, o6, 0, 0, 0);
    o7 = __builtin_amdgcn_mfma_f32_16x16x16f16(p, bv7, o7, 0, 0, 0);
  }

  // ---- O store: O[q0 + 4lg + r][16dt + lr] = o[dt][r] * inv4[r] ----
  float* obase = outO + ((size_t)b * S_ + q0 + 4 * lg) * D_ + lr;
#pragma unroll
  for (int r = 0; r < 4; ++r) {
    float* orow = obase + (size_t)r * D_;
    orow[0]   = o0[r] * inv4[r];
    orow[16]  = o1[r] * inv4[r];
    orow[32]  = o2[r] * inv4[r];
    orow[48]  = o3[r] * inv4[r];
    orow[64]  = o4[r] * inv4[r];
    orow[80]  = o5[r] * inv4[r];
    orow[96]  = o6[r] * inv4[r];
    orow[112] = o7[r] * inv4[r];
  }
}

extern "C" void kernel_launch(void* const* d_in, const int* in_sizes, int n_in,
                              void* d_out, int out_size, void* d_ws, size_t ws_size,
                              hipStream_t stream) {
  const float* Q = (const float*)d_in[0];
  const float* K = (const float*)d_in[1];
  const float* V = (const float*)d_in[2];
  float* outO = (float*)d_out;
  float* outA = outO + NE_;

  const size_t inv_elems = (size_t)B_ * S_;                  // 32K floats
  const size_t need = 2 * NE_ * sizeof(_Float16) + inv_elems * sizeof(float);

  if (ws_size >= need) {
    _Float16* Kh  = (_Float16*)d_ws;
    _Float16* Vt2 = Kh + NE_;
    float* invbuf = (float*)(Vt2 + NE_);
    prepass_kernel<<<3072, 256, 0, stream>>>(K, V, Kh, Vt2);
    sums_kernel<true><<<256, 256, 0, stream>>>(Q, nullptr, Kh, invbuf);
    attn_main<true><<<512, 256, 0, stream>>>(Q, nullptr, nullptr,
                                             Kh, Vt2, invbuf, outO, outA);
  } else {
    // fallback: read f32 directly; only needs 128KB ws for invbuf
    float* invbuf = (float*)d_ws;
    sums_kernel<false><<<256, 256, 0, stream>>>(Q, K, nullptr, invbuf);
    attn_main<false><<<512, 256, 0, stream>>>(Q, K, V,
                                              nullptr, nullptr, invbuf, outO, outA);
  }
}

// Round 11
// 189.777 us; speedup vs baseline: 1.4390x; 1.4390x over previous
//
#include <hip/hip_runtime.h>
#include <cstdint>
#include <cstddef>

#define B_ 16
#define S_ 2048
#define D_ 128
#define OST 136          // opart row stride in halves

typedef float  f32x4 __attribute__((ext_vector_type(4)));
typedef _Float16 f16x8 __attribute__((ext_vector_type(8)));
typedef _Float16 f16x4 __attribute__((ext_vector_type(4)));

// log2(e) / sqrt(128)
#define SCALE_ 0.12751743f

#define NE_ ((size_t)B_ * S_ * D_)   // 4,194,304 per tensor
#define VT2_BATCH 262144             // halves per batch in Vt2 (=512KB f16)

// ---------------- pre-pass (verified R5-R10) ----------------
// blocks [0,2048): V -> Vt2, PV-fragment-native tiled layout:
//   Vt2[((b*128 + kt)*8 + dt)*64 + lane][i]  (f16, i=0..3)
//   holds V[b][key = kt*16 + 4*(lane>>4) + i][d = dt*16 + (lane&15)]
// blocks [2048,3072): K f32 -> f16 row-major
__global__ void prepass_kernel(const float* __restrict__ K,
                               const float* __restrict__ V,
                               _Float16* __restrict__ Kh,
                               _Float16* __restrict__ Vt2) {
  const int blk = blockIdx.x;
  if (blk < 2048) {
    const int b  = blk >> 7;
    const int kt = blk & 127;
    const int tid = threadIdx.x;
    const int lg = tid >> 6;
    const int i  = (tid >> 4) & 3;
    const int lr = tid & 15;
    const size_t vrow = ((size_t)b * S_ + kt * 16 + 4 * lg + i) * D_;
    const size_t obase = (((size_t)(b * 128 + kt) * 8) * 64 + lg * 16 + lr) * 4 + i;
#pragma unroll
    for (int dt = 0; dt < 8; ++dt) {
      float val = V[vrow + dt * 16 + lr];
      Vt2[obase + (size_t)dt * 256] = (_Float16)val;
    }
  } else {
    int rel = blk - 2048;
    const int n4 = (int)(NE_ / 4);
    for (int i = rel * 256 + (int)threadIdx.x; i < n4; i += 1024 * 256) {
      f32x4 v = ((const f32x4*)K)[i];
      f16x4 h;
      for (int j = 0; j < 4; ++j) h[j] = (_Float16)v[j];
      ((f16x4*)Kh)[i] = h;
    }
  }
}

// ---------------- kernel 2: row-sum denominators ----------------
// 1024 blocks x 4 waves. Block owns 32 q-rows; wave w covers keys
// [512w, 512w+512). Swapped QK^T; per-lane psum reduced over lg via
// shfl, 4 wave-partials reduced via LDS (fixed order). inv = 1/sum.
template <bool WS>
__global__ __launch_bounds__(256, 4)
void sums_kernel(const float* __restrict__ Qf, const float* __restrict__ Kf,
                 const _Float16* __restrict__ Kh, float* __restrict__ invbuf) {
  __shared__ float ssum[4][32];
  const int tid = threadIdx.x;
  const int w = tid >> 6, lane = tid & 63, lg = lane >> 4, lr = lane & 15;
  const int blk = blockIdx.x;
  const int gwid = (blk & 7) * 128 + (blk >> 3);   // XCD-local: b in {2x,2x+1}
  const int b  = gwid >> 6;
  const int q0 = (gwid & 63) * 32;
  const int key0 = w * 512;

  f16x8 bq[2][4];
#pragma unroll
  for (int h = 0; h < 2; ++h) {
    const float* qp = Qf + ((size_t)b * S_ + q0 + 16 * h + lr) * D_;
#pragma unroll
    for (int kk = 0; kk < 4; ++kk) {
      const float* p = qp + kk * 32 + lg * 8;
      f32x4 v0 = *(const f32x4*)p, v1 = *(const f32x4*)(p + 4);
      f16x8 a;
#pragma unroll
      for (int j = 0; j < 4; ++j) { a[j] = (_Float16)v0[j]; a[4 + j] = (_Float16)v1[j]; }
      bq[h][kk] = a;
    }
  }

  float psum0 = 0.f, psum1 = 0.f;
#pragma unroll 2
  for (int kt = 0; kt < 32; ++kt) {
    f32x4 acc0 = {0.f, 0.f, 0.f, 0.f}, acc1 = {0.f, 0.f, 0.f, 0.f};
    const size_t krow = (size_t)b * S_ + key0 + kt * 16 + lr;
#pragma unroll
    for (int kk = 0; kk < 4; ++kk) {
      f16x8 ka;
      if constexpr (WS) {
        ka = *(const f16x8*)(Kh + krow * D_ + kk * 32 + lg * 8);
      } else {
        const float* p = Kf + krow * D_ + kk * 32 + lg * 8;
        f32x4 v0 = *(const f32x4*)p, v1 = *(const f32x4*)(p + 4);
#pragma unroll
        for (int j = 0; j < 4; ++j) { ka[j] = (_Float16)v0[j]; ka[4 + j] = (_Float16)v1[j]; }
      }
      acc0 = __builtin_amdgcn_mfma_f32_16x16x32_f16(ka, bq[0][kk], acc0, 0, 0, 0);
      acc1 = __builtin_amdgcn_mfma_f32_16x16x32_f16(ka, bq[1][kk], acc1, 0, 0, 0);
    }
#pragma unroll
    for (int r = 0; r < 4; ++r) {
      psum0 += __builtin_amdgcn_exp2f(acc0[r] * SCALE_);
      psum1 += __builtin_amdgcn_exp2f(acc1[r] * SCALE_);
    }
  }
  psum0 += __shfl_xor(psum0, 16); psum0 += __shfl_xor(psum0, 32);
  psum1 += __shfl_xor(psum1, 16); psum1 += __shfl_xor(psum1, 32);
  if (lg == 0) { ssum[w][lr] = psum0; ssum[w][16 + lr] = psum1; }
  __syncthreads();
  if (tid < 32) {
    float s = ssum[0][tid] + ssum[1][tid] + ssum[2][tid] + ssum[3][tid];
    invbuf[(size_t)b * S_ + q0 + tid] = 1.0f / s;
  }
}

// ---------------- kernel 3: streaming attention ----------------
// 1024 blocks x 4 waves. Block owns 32 q-rows; wave w covers keys
// [512w, 512w+512) -> every K/V fragment load is amortized over 32 rows
// (halves vector-load traffic vs 16-row waves) and 4096 waves give
// ~12-16 waves/CU. inv precomputed -> normalized attn rows stream out
// NT from iteration 0 (no convoy, L2 protected). O partials per wave in
// regs; single end-of-kernel 4-way LDS reduction (one barrier, off the
// hot path). All reg arrays fully unrolled (R5/R6 scratch lesson).
// Fragment math verbatim from verified R5-R10.
template <bool WS>
__global__ __launch_bounds__(256, 3)
void attn_main(const float* __restrict__ Qf, const float* __restrict__ Kf,
               const float* __restrict__ Vf,
               const _Float16* __restrict__ Kh, const _Float16* __restrict__ Vt2,
               const float* __restrict__ invbuf,
               float* __restrict__ outO, float* __restrict__ outA) {
  __shared__ _Float16 opart[4][32][OST];   // 34.8 KB
  const int tid = threadIdx.x;
  const int w = tid >> 6, lane = tid & 63, lg = lane >> 4, lr = lane & 15;
  const int blk = blockIdx.x;
  const int gwid = (blk & 7) * 128 + (blk >> 3);   // XCD-local: b in {2x,2x+1}
  const int b  = gwid >> 6;
  const int q0 = (gwid & 63) * 32;
  const int key0 = w * 512;

  const float inv0 = invbuf[(size_t)b * S_ + q0 + lr];
  const float inv1 = invbuf[(size_t)b * S_ + q0 + 16 + lr];

  // Q B-frags: B[k=32kk+8lg+j][n=qrow=16h+lr]
  f16x8 bq[2][4];
#pragma unroll
  for (int h = 0; h < 2; ++h) {
    const float* qp = Qf + ((size_t)b * S_ + q0 + 16 * h + lr) * D_;
#pragma unroll
    for (int kk = 0; kk < 4; ++kk) {
      const float* p = qp + kk * 32 + lg * 8;
      f32x4 v0 = *(const f32x4*)p, v1 = *(const f32x4*)(p + 4);
      f16x8 a;
#pragma unroll
      for (int j = 0; j < 4; ++j) { a[j] = (_Float16)v0[j]; a[4 + j] = (_Float16)v1[j]; }
      bq[h][kk] = a;
    }
  }

  f32x4 o[2][8] = {};

  const _Float16* vbase = nullptr;
  if constexpr (WS)
    vbase = Vt2 + (size_t)b * VT2_BATCH + (size_t)(key0 >> 4) * 2048 + lane * 4;
  float* arow0 = outA + ((size_t)b * S_ + q0 + lr) * S_ + key0 + lg * 4;
  float* arow1 = arow0 + (size_t)16 * S_;

#pragma unroll 2
  for (int kt = 0; kt < 32; ++kt) {
    // ---- QK^T tile (both 16-row halves share ka) ----
    f32x4 acc0 = {0.f, 0.f, 0.f, 0.f}, acc1 = {0.f, 0.f, 0.f, 0.f};
    const size_t krow = (size_t)b * S_ + key0 + kt * 16 + lr;
#pragma unroll
    for (int kk = 0; kk < 4; ++kk) {
      f16x8 ka;
      if constexpr (WS) {
        ka = *(const f16x8*)(Kh + krow * D_ + kk * 32 + lg * 8);
      } else {
        const float* p = Kf + krow * D_ + kk * 32 + lg * 8;
        f32x4 v0 = *(const f32x4*)p, v1 = *(const f32x4*)(p + 4);
#pragma unroll
        for (int j = 0; j < 4; ++j) { ka[j] = (_Float16)v0[j]; ka[4 + j] = (_Float16)v1[j]; }
      }
      acc0 = __builtin_amdgcn_mfma_f32_16x16x32_f16(ka, bq[0][kk], acc0, 0, 0, 0);
      acc1 = __builtin_amdgcn_mfma_f32_16x16x32_f16(ka, bq[1][kk], acc1, 0, 0, 0);
    }
    // ---- exp, immediate normalized NT attn store, f16 pack ----
    f32x4 av0, av1; f16x4 p0, p1;
#pragma unroll
    for (int r = 0; r < 4; ++r) {
      float e0 = __builtin_amdgcn_exp2f(acc0[r] * SCALE_);
      float e1 = __builtin_amdgcn_exp2f(acc1[r] * SCALE_);
      av0[r] = e0 * inv0;  p0[r] = (_Float16)e0;
      av1[r] = e1 * inv1;  p1[r] = (_Float16)e1;
    }
    __builtin_nontemporal_store(av0, (f32x4*)(arow0 + kt * 16));
    __builtin_nontemporal_store(av1, (f32x4*)(arow1 + kt * 16));
    // ---- PV accumulate: p0/p1 ARE the 16x16x16 A-frags; bv shared ----
    f16x4 bv0, bv1, bv2, bv3, bv4, bv5, bv6, bv7;
    if constexpr (WS) {
      const _Float16* vk = vbase + (size_t)kt * 2048;
      bv0 = *(const f16x4*)(vk);        bv1 = *(const f16x4*)(vk + 256);
      bv2 = *(const f16x4*)(vk + 512);  bv3 = *(const f16x4*)(vk + 768);
      bv4 = *(const f16x4*)(vk + 1024); bv5 = *(const f16x4*)(vk + 1280);
      bv6 = *(const f16x4*)(vk + 1536); bv7 = *(const f16x4*)(vk + 1792);
    } else {
      const float* vrow = Vf + ((size_t)b * S_ + key0 + kt * 16 + 4 * lg) * D_ + lr;
#pragma unroll
      for (int i = 0; i < 4; ++i) {
        bv0[i] = (_Float16)vrow[(size_t)i * D_];
        bv1[i] = (_Float16)vrow[(size_t)i * D_ + 16];
        bv2[i] = (_Float16)vrow[(size_t)i * D_ + 32];
        bv3[i] = (_Float16)vrow[(size_t)i * D_ + 48];
        bv4[i] = (_Float16)vrow[(size_t)i * D_ + 64];
        bv5[i] = (_Float16)vrow[(size_t)i * D_ + 80];
        bv6[i] = (_Float16)vrow[(size_t)i * D_ + 96];
        bv7[i] = (_Float16)vrow[(size_t)i * D_ + 112];
      }
    }
    o[0][0] = __builtin_amdgcn_mfma_f32_16x16x16f16(p0, bv0, o[0][0], 0, 0, 0);
    o[0][1] = __builtin_amdgcn_mfma_f32_16x16x16f16(p0, bv1, o[0][1], 0, 0, 0);
    o[0][2] = __builtin_amdgcn_mfma_f32_16x16x16f16(p0, bv2, o[0][2], 0, 0, 0);
    o[0][3] = __builtin_amdgcn_mfma_f32_16x16x16f16(p0, bv3, o[0][3], 0, 0, 0);
    o[0][4] = __builtin_amdgcn_mfma_f32_16x16x16f16(p0, bv4, o[0][4], 0, 0, 0);
    o[0][5] = __builtin_amdgcn_mfma_f32_16x16x16f16(p0, bv5, o[0][5], 0, 0, 0);
    o[0][6] = __builtin_amdgcn_mfma_f32_16x16x16f16(p0, bv6, o[0][6], 0, 0, 0);
    o[0][7] = __builtin_amdgcn_mfma_f32_16x16x16f16(p0, bv7, o[0][7], 0, 0, 0);
    o[1][0] = __builtin_amdgcn_mfma_f32_16x16x16f16(p1, bv0, o[1][0], 0, 0, 0);
    o[1][1] = __builtin_amdgcn_mfma_f32_16x16x16f16(p1, bv1, o[1][1], 0, 0, 0);
    o[1][2] = __builtin_amdgcn_mfma_f32_16x16x16f16(p1, bv2, o[1][2], 0, 0, 0);
    o[1][3] = __builtin_amdgcn_mfma_f32_16x16x16f16(p1, bv3, o[1][3], 0, 0, 0);
    o[1][4] = __builtin_amdgcn_mfma_f32_16x16x16f16(p1, bv4, o[1][4], 0, 0, 0);
    o[1][5] = __builtin_amdgcn_mfma_f32_16x16x16f16(p1, bv5, o[1][5], 0, 0, 0);
    o[1][6] = __builtin_amdgcn_mfma_f32_16x16x16f16(p1, bv6, o[1][6], 0, 0, 0);
    o[1][7] = __builtin_amdgcn_mfma_f32_16x16x16f16(p1, bv7, o[1][7], 0, 0, 0);
  }

  // ---- O partials -> LDS (once; off hot path). D layout:
  //      lane holds O[qrow-in-half = 4lg+r][d = 16dt+lr] ----
#pragma unroll
  for (int h = 0; h < 2; ++h)
#pragma unroll
    for (int dt = 0; dt < 8; ++dt)
#pragma unroll
      for (int r = 0; r < 4; ++r)
        opart[w][h * 16 + 4 * lg + r][dt * 16 + lr] = (_Float16)o[h][dt][r];

  __syncthreads();   // the ONLY barrier

  // ---- O: fixed-order 4-way reduction, 64B/thread store ----
  {
    const int row = tid >> 3;          // 0..31
    const int dc  = (tid & 7) * 16;    // 0..112
    float racc[16] = {};
#pragma unroll
    for (int wv = 0; wv < 4; ++wv) {
      f16x8 x0 = *(const f16x8*)&opart[wv][row][dc];
      f16x8 x1 = *(const f16x8*)&opart[wv][row][dc + 8];
#pragma unroll
      for (int j = 0; j < 8; ++j) { racc[j] += (float)x0[j]; racc[8 + j] += (float)x1[j]; }
    }
    const float inv = invbuf[(size_t)b * S_ + q0 + row];
    float* op = outO + ((size_t)b * S_ + q0 + row) * D_ + dc;
#pragma unroll
    for (int v = 0; v < 4; ++v) {
      f32x4 rv;
#pragma unroll
      for (int j = 0; j < 4; ++j) rv[j] = racc[4 * v + j] * inv;
      *(f32x4*)(op + 4 * v) = rv;
    }
  }
}

extern "C" void kernel_launch(void* const* d_in, const int* in_sizes, int n_in,
                              void* d_out, int out_size, void* d_ws, size_t ws_size,
                              hipStream_t stream) {
  const float* Q = (const float*)d_in[0];
  const float* K = (const float*)d_in[1];
  const float* V = (const float*)d_in[2];
  float* outO = (float*)d_out;
  float* outA = outO + NE_;

  const size_t inv_elems = (size_t)B_ * S_;
  const size_t need = 2 * NE_ * sizeof(_Float16) + inv_elems * sizeof(float);

  if (ws_size >= need) {
    _Float16* Kh  = (_Float16*)d_ws;
    _Float16* Vt2 = Kh + NE_;
    float* invbuf = (float*)(Vt2 + NE_);
    prepass_kernel<<<3072, 256, 0, stream>>>(K, V, Kh, Vt2);
    sums_kernel<true><<<1024, 256, 0, stream>>>(Q, nullptr, Kh, invbuf);
    attn_main<true><<<1024, 256, 0, stream>>>(Q, nullptr, nullptr,
                                              Kh, Vt2, invbuf, outO, outA);
  } else {
    float* invbuf = (float*)d_ws;
    sums_kernel<false><<<1024, 256, 0, stream>>>(Q, K, nullptr, invbuf);
    attn_main<false><<<1024, 256, 0, stream>>>(Q, K, V,
                                               nullptr, nullptr, invbuf, outO, outA);
  }
}